// Round 1
// baseline (1151.846 us; speedup 1.0000x reference)
//
#include <hip/hip_runtime.h>
#include <math.h>

#define NPTS 80000
#define NBH 32
#define KP 15
#define CIN 128
#define COUT 256
#define D2 64
#define INFL 0.4f
#define EPS 1e-5f
#define SLOPE 0.2f

// ---------------- generic tiled f32 GEMM: C[rows x CO] = A[rows x CI] * B[CI x CO]
// rows divisible by 64, CI divisible by 32, CO divisible by 64.
__global__ __launch_bounds__(256) void k_gemm(const float* __restrict__ A,
                                              const float* __restrict__ B,
                                              float* __restrict__ C,
                                              int rows, int CIv, int COv) {
  __shared__ float As[64][33];
  __shared__ float Bs[32][64];
  int tid = threadIdx.x;
  int row0 = blockIdx.x * 64;
  int c0 = blockIdx.y * 64;
  int tc = tid & 15, tr = tid >> 4;
  float acc[4][4] = {};
  for (int k0 = 0; k0 < CIv; k0 += 32) {
#pragma unroll
    for (int j = 0; j < 8; ++j) {
      int flat = j * 256 + tid;
      int r = flat >> 5, kk = flat & 31;
      As[r][kk] = A[(size_t)(row0 + r) * CIv + k0 + kk];
    }
#pragma unroll
    for (int j = 0; j < 8; ++j) {
      int flat = j * 256 + tid;
      int kk = flat >> 6, c = flat & 63;
      Bs[kk][c] = B[(size_t)(k0 + kk) * COv + c0 + c];
    }
    __syncthreads();
#pragma unroll
    for (int kk = 0; kk < 32; ++kk) {
      float4 bv = *reinterpret_cast<const float4*>(&Bs[kk][tc * 4]);
#pragma unroll
      for (int i = 0; i < 4; ++i) {
        float av = As[tr * 4 + i][kk];
        acc[i][0] += av * bv.x;
        acc[i][1] += av * bv.y;
        acc[i][2] += av * bv.z;
        acc[i][3] += av * bv.w;
      }
    }
    __syncthreads();
  }
#pragma unroll
  for (int i = 0; i < 4; ++i) {
    float4 v = make_float4(acc[i][0], acc[i][1], acc[i][2], acc[i][3]);
    *reinterpret_cast<float4*>(&C[(size_t)(row0 + tr * 4 + i) * COv + c0 + tc * 4]) = v;
  }
}

// ---------------- per-column sum / sumsq (for batch-norm stats), atomicAdd into sum/sumsq
__global__ __launch_bounds__(256) void k_colstats(const float* __restrict__ X, int total,
                                                  int cols, float* __restrict__ sum,
                                                  float* __restrict__ sumsq) {
  __shared__ float ls[256], ls2[256];
  int tid = threadIdx.x;
  int stride = gridDim.x * 256;  // multiple of cols (cols in {64,256})
  float s = 0.f, s2 = 0.f;
  for (int i = blockIdx.x * 256 + tid; i < total; i += stride) {
    float v = X[i];
    s += v;
    s2 += v * v;
  }
  ls[tid] = s;
  ls2[tid] = s2;
  __syncthreads();
  if (tid < cols) {
    float a = ls[tid], a2 = ls2[tid];
    for (int j = tid + cols; j < 256; j += cols) {
      a += ls[j];
      a2 += ls2[j];
    }
    atomicAdd(&sum[tid], a);
    atomicAdd(&sumsq[tid], a2);
  }
}

// ---------------- in-place batchnorm + optional leaky relu
__global__ __launch_bounds__(256) void k_norm_act(float* __restrict__ X, int rows, int cols,
                                                  const float* __restrict__ sum,
                                                  const float* __restrict__ sumsq,
                                                  const float* __restrict__ g,
                                                  const float* __restrict__ b, int do_act) {
  __shared__ float sc[256], sh[256];
  int tid = threadIdx.x;
  if (tid < cols) {
    float m = sum[tid] / rows;
    float v = sumsq[tid] / rows - m * m;
    float s = g[tid] * rsqrtf(v + EPS);
    sc[tid] = s;
    sh[tid] = b[tid] - m * s;
  }
  __syncthreads();
  int total4 = rows * cols / 4;
  int c4n = cols / 4;
  int stride = gridDim.x * 256;
  float4* X4 = reinterpret_cast<float4*>(X);
  for (int i = blockIdx.x * 256 + tid; i < total4; i += stride) {
    int cb = (i % c4n) * 4;
    float4 v = X4[i];
    v.x = v.x * sc[cb + 0] + sh[cb + 0];
    v.y = v.y * sc[cb + 1] + sh[cb + 1];
    v.z = v.z * sc[cb + 2] + sh[cb + 2];
    v.w = v.w * sc[cb + 3] + sh[cb + 3];
    if (do_act) {
      v.x = v.x > 0.f ? v.x : SLOPE * v.x;
      v.y = v.y > 0.f ? v.y : SLOPE * v.y;
      v.z = v.z > 0.f ? v.z : SLOPE * v.z;
      v.w = v.w > 0.f ? v.w : SLOPE * v.w;
    }
    X4[i] = v;
  }
}

// ---------------- KPConv: 8 points per block, 512 threads
__global__ __launch_bounds__(512) void k_kpconv(const float* __restrict__ X1,
                                                const float* __restrict__ xyz,
                                                const int* __restrict__ nidx,
                                                const float* __restrict__ kpp,
                                                const float* __restrict__ kw,
                                                float* __restrict__ Y2) {
  __shared__ int s_idx[8][32];
  __shared__ float s_w[8][32][16];   // 15 kernel pts, padded to 16
  __shared__ float s_fk[8][15][64];
  __shared__ float s_kw[64 * 64];
  int tid = threadIdx.x;
  int n0 = blockIdx.x * 8;

  // ---- phase A: influence weights w[p][h][k]
  if (tid < 256) {
    int p = tid >> 5, h = tid & 31;
    int n = n0 + p;
    int nb = nidx[n * NBH + h];
    s_idx[p][h] = nb;
    float px = xyz[n * 3 + 0], py = xyz[n * 3 + 1], pz = xyz[n * 3 + 2];
    float rx = xyz[nb * 3 + 0] - px;
    float ry = xyz[nb * 3 + 1] - py;
    float rz = xyz[nb * 3 + 2] - pz;
#pragma unroll
    for (int k = 0; k < 15; ++k) {
      float dx = rx - kpp[k * 3 + 0];
      float dy = ry - kpp[k * 3 + 1];
      float dz = rz - kpp[k * 3 + 2];
      float dist = sqrtf(dx * dx + dy * dy + dz * dz);
      s_w[p][h][k] = fmaxf(1.0f - dist * (1.0f / INFL), 0.0f);
    }
    s_w[p][h][15] = 0.0f;
  }
  __syncthreads();

  // ---- phase B: fk[p][k][d] = sum_h w[p][h][k] * x1[idx[p][h]][d]
  int p = tid >> 6, d = tid & 63;
  float fk[15];
#pragma unroll
  for (int k = 0; k < 15; ++k) fk[k] = 0.f;
  for (int h = 0; h < NBH; ++h) {
    int nb = s_idx[p][h];
    float v = X1[(size_t)nb * 64 + d];
    const float4* wp = reinterpret_cast<const float4*>(&s_w[p][h][0]);
    float4 w0 = wp[0], w1 = wp[1], w2 = wp[2], w3 = wp[3];
    fk[0] += w0.x * v;  fk[1] += w0.y * v;  fk[2] += w0.z * v;  fk[3] += w0.w * v;
    fk[4] += w1.x * v;  fk[5] += w1.y * v;  fk[6] += w1.z * v;  fk[7] += w1.w * v;
    fk[8] += w2.x * v;  fk[9] += w2.y * v;  fk[10] += w2.z * v; fk[11] += w2.w * v;
    fk[12] += w3.x * v; fk[13] += w3.y * v; fk[14] += w3.z * v;
  }
#pragma unroll
  for (int k = 0; k < 15; ++k) s_fk[p][k][d] = fk[k];
  __syncthreads();

  // ---- phase C: out[p][e] = sum_k sum_d fk[p][k][d] * kw[k][d][e]  (e == this thread's d slot)
  float acc = 0.f;
  for (int k = 0; k < 15; ++k) {
#pragma unroll
    for (int j = 0; j < 8; ++j) s_kw[j * 512 + tid] = kw[(size_t)k * 4096 + j * 512 + tid];
    __syncthreads();
#pragma unroll
    for (int d4 = 0; d4 < 16; ++d4) {
      float4 f = *reinterpret_cast<const float4*>(&s_fk[p][k][d4 * 4]);
      acc += f.x * s_kw[(d4 * 4 + 0) * 64 + d];
      acc += f.y * s_kw[(d4 * 4 + 1) * 64 + d];
      acc += f.z * s_kw[(d4 * 4 + 2) * 64 + d];
      acc += f.w * s_kw[(d4 * 4 + 3) * 64 + d];
    }
    __syncthreads();
  }
  Y2[(size_t)(n0 + p) * 64 + d] = acc;
}

// ---------------- final: out = leaky(bn(Y3)) + bn(YSC)
__global__ __launch_bounds__(256) void k_final(const float* __restrict__ Y3,
                                               const float* __restrict__ YSC,
                                               const float* __restrict__ s3,
                                               const float* __restrict__ ss3,
                                               const float* __restrict__ g2,
                                               const float* __restrict__ b2,
                                               const float* __restrict__ ssc,
                                               const float* __restrict__ sssc,
                                               const float* __restrict__ gsc,
                                               const float* __restrict__ bsc,
                                               float* __restrict__ out) {
  __shared__ float sc3[256], sh3[256], scc[256], shc[256];
  int tid = threadIdx.x;
  {
    float m = s3[tid] * (1.0f / NPTS);
    float v = ss3[tid] * (1.0f / NPTS) - m * m;
    float s = g2[tid] * rsqrtf(v + EPS);
    sc3[tid] = s;
    sh3[tid] = b2[tid] - m * s;
    m = ssc[tid] * (1.0f / NPTS);
    v = sssc[tid] * (1.0f / NPTS) - m * m;
    s = gsc[tid] * rsqrtf(v + EPS);
    scc[tid] = s;
    shc[tid] = bsc[tid] - m * s;
  }
  __syncthreads();
  int total4 = NPTS * COUT / 4;
  int stride = gridDim.x * 256;
  const float4* A4 = reinterpret_cast<const float4*>(Y3);
  const float4* B4 = reinterpret_cast<const float4*>(YSC);
  float4* O4 = reinterpret_cast<float4*>(out);
  for (int i = blockIdx.x * 256 + tid; i < total4; i += stride) {
    int cb = (i & 63) * 4;  // 64 float4 per 256-col row
    float4 a = A4[i];
    float4 b = B4[i];
    float o0 = a.x * sc3[cb + 0] + sh3[cb + 0]; o0 = o0 > 0.f ? o0 : SLOPE * o0; o0 += b.x * scc[cb + 0] + shc[cb + 0];
    float o1 = a.y * sc3[cb + 1] + sh3[cb + 1]; o1 = o1 > 0.f ? o1 : SLOPE * o1; o1 += b.y * scc[cb + 1] + shc[cb + 1];
    float o2 = a.z * sc3[cb + 2] + sh3[cb + 2]; o2 = o2 > 0.f ? o2 : SLOPE * o2; o2 += b.z * scc[cb + 2] + shc[cb + 2];
    float o3 = a.w * sc3[cb + 3] + sh3[cb + 3]; o3 = o3 > 0.f ? o3 : SLOPE * o3; o3 += b.w * scc[cb + 3] + shc[cb + 3];
    O4[i] = make_float4(o0, o1, o2, o3);
  }
}

extern "C" void kernel_launch(void* const* d_in, const int* in_sizes, int n_in,
                              void* d_out, int out_size, void* d_ws, size_t ws_size,
                              hipStream_t stream) {
  const float* feats = (const float*)d_in[0];
  const float* xyz   = (const float*)d_in[1];
  // d_in[2] = batch (unused, single batch)
  const int* nidx    = (const int*)d_in[3];
  const float* W1    = (const float*)d_in[4];
  const float* g1    = (const float*)d_in[5];
  const float* b1    = (const float*)d_in[6];
  const float* kpp   = (const float*)d_in[7];
  const float* kw    = (const float*)d_in[8];
  const float* W2    = (const float*)d_in[9];
  const float* g2    = (const float*)d_in[10];
  const float* b2    = (const float*)d_in[11];
  const float* Wsc   = (const float*)d_in[12];
  const float* gsc   = (const float*)d_in[13];
  const float* bsc   = (const float*)d_in[14];
  float* out = (float*)d_out;

  // workspace layout (floats): X1[N*64] | Y2[N*64] | Y3[N*256] | YSC[N*256] | stats[1152]
  float* X1  = (float*)d_ws;
  float* Y2  = X1 + (size_t)NPTS * D2;
  float* Y3  = Y2 + (size_t)NPTS * D2;
  float* YSC = Y3 + (size_t)NPTS * COUT;
  float* ST  = YSC + (size_t)NPTS * COUT;
  float* S1 = ST, *SS1 = ST + 64;
  float* S3 = ST + 128, *SS3 = ST + 384;
  float* SSC = ST + 640, *SSSC = ST + 896;

  hipMemsetAsync(ST, 0, 1152 * sizeof(float), stream);

  // unary_1 linear
  k_gemm<<<dim3(1250, 1), 256, 0, stream>>>(feats, W1, X1, NPTS, CIN, D2);
  k_colstats<<<512, 256, 0, stream>>>(X1, NPTS * D2, D2, S1, SS1);
  k_norm_act<<<1024, 256, 0, stream>>>(X1, NPTS, D2, S1, SS1, g1, b1, 1);
  // KPConv
  k_kpconv<<<NPTS / 8, 512, 0, stream>>>(X1, xyz, nidx, kpp, kw, Y2);
  // unary_2 linear
  k_gemm<<<dim3(1250, 4), 256, 0, stream>>>(Y2, W2, Y3, NPTS, D2, COUT);
  k_colstats<<<512, 256, 0, stream>>>(Y3, NPTS * COUT, COUT, S3, SS3);
  // shortcut linear
  k_gemm<<<dim3(1250, 4), 256, 0, stream>>>(feats, Wsc, YSC, NPTS, CIN, COUT);
  k_colstats<<<512, 256, 0, stream>>>(YSC, NPTS * COUT, COUT, SSC, SSSC);
  // bn+act+add
  k_final<<<2048, 256, 0, stream>>>(Y3, YSC, S3, SS3, g2, b2, SSC, SSSC, gsc, bsc, out);
}

// Round 2
// 532.983 us; speedup vs baseline: 2.1611x; 2.1611x over previous
//
#include <hip/hip_runtime.h>
#include <math.h>

#define NPTS 80000
#define NBH 32
#define KP 15
#define CIN 128
#define COUT 256
#define D2 64
#define INFL 0.4f
#define EPS 1e-5f
#define SLOPE 0.2f

typedef __attribute__((ext_vector_type(8))) short short8;
typedef __attribute__((ext_vector_type(4))) float f32x4;

__device__ inline ushort f2b(float x) {
  unsigned u = __float_as_uint(x);
  return (ushort)((u + 0x7FFFu + ((u >> 16) & 1u)) >> 16);  // RNE
}
__device__ inline float b2f(ushort v) { return __uint_as_float(((unsigned)v) << 16); }

// ---------------- prep: feats f32->bf16, weights f32->bf16 swizzled to MFMA B-operand order
// B fragment order: Bsw[chunk][ctile][nn][q][j] <- B[k][n], k=chunk*32+q*8+j, n=ctile*16+nn
__global__ __launch_bounds__(256) void k_prep(const float* __restrict__ feats,
                                              const float* __restrict__ W1,
                                              const float* __restrict__ W2,
                                              const float* __restrict__ Wsc,
                                              const float* __restrict__ kw,
                                              ushort* __restrict__ featsb,
                                              ushort* __restrict__ w1s,
                                              ushort* __restrict__ w2s,
                                              ushort* __restrict__ wscs,
                                              ushort* __restrict__ kws) {
  const int NF4 = NPTS * CIN / 4;  // 2,560,000 float4s
  const int TOT = NF4 + 118784;
  int stride = gridDim.x * 256;
  for (int i = blockIdx.x * 256 + threadIdx.x; i < TOT; i += stride) {
    if (i < NF4) {
      float4 v = reinterpret_cast<const float4*>(feats)[i];
      ushort4 o;
      o.x = f2b(v.x); o.y = f2b(v.y); o.z = f2b(v.z); o.w = f2b(v.w);
      reinterpret_cast<ushort4*>(featsb)[i] = o;
    } else {
      int j = i - NF4;
      const float* src;
      ushort* dst;
      int logN;
      if (j < 8192)       { src = W1;  dst = w1s;  logN = 6; }
      else if (j < 24576) { j -= 8192;  src = W2;  dst = w2s;  logN = 8; }
      else if (j < 57344) { j -= 24576; src = Wsc; dst = wscs; logN = 8; }
      else                { j -= 57344; src = kw;  dst = kws;  logN = 6; }
      int N = 1 << logN, NT = N >> 4;
      int k = j >> logN, n = j & (N - 1);
      int dsti = ((k >> 5) * NT + (n >> 4)) * 512 + (n & 15) * 32 + ((k >> 3) & 3) * 8 + (k & 7);
      dst[dsti] = f2b(src[j]);
    }
  }
}

// ---------------- register-resident MFMA GEMM: C[M x NCOLS] = A[M x K] * B[K x NCOLS]
// A bf16 row-major, B pre-swizzled bf16 (k_prep). No LDS, no barriers.
// wave w of block owns rows [blk*64 + w*16, +16). M % 64 == 0, K % 32 == 0.
template <int NCOLS, int OUTB>
__global__ __launch_bounds__(256) void k_gemm_mfma(const ushort* __restrict__ A,
                                                   const ushort* __restrict__ Bsw,
                                                   float* __restrict__ Cf,
                                                   ushort* __restrict__ Cb, int K) {
  constexpr int NT = NCOLS / 16;
  int tid = threadIdx.x;
  int wave = tid >> 6, lane = tid & 63;
  int nn = lane & 15, q = lane >> 4;
  int row0 = blockIdx.x * 64 + wave * 16;
  f32x4 acc[NT];
#pragma unroll
  for (int c = 0; c < NT; ++c) acc[c] = (f32x4){0.f, 0.f, 0.f, 0.f};
  // A fragment: lane holds A[row0+nn][ch*32 + q*8 + j], j=0..7 (16B contiguous)
  const ushort* ap = A + (size_t)(row0 + nn) * K + q * 8;
  int nch = K >> 5;
  for (int ch = 0; ch < nch; ++ch) {
    short8 af = *reinterpret_cast<const short8*>(ap + (size_t)ch * 32);
    const ushort* bp = Bsw + (size_t)ch * NT * 512 + nn * 32 + q * 8;
#pragma unroll
    for (int c = 0; c < NT; ++c) {
      short8 bf = *reinterpret_cast<const short8*>(bp + c * 512);
      acc[c] = __builtin_amdgcn_mfma_f32_16x16x32_bf16(af, bf, acc[c], 0, 0, 0);
    }
  }
  // C/D layout: col = c*16 + (lane&15), row = (lane>>4)*4 + reg
#pragma unroll
  for (int c = 0; c < NT; ++c) {
#pragma unroll
    for (int r = 0; r < 4; ++r) {
      size_t idx = (size_t)(row0 + q * 4 + r) * NCOLS + c * 16 + nn;
      if (OUTB) Cb[idx] = f2b(acc[c][r]);
      else      Cf[idx] = acc[c][r];
    }
  }
}

// ---------------- per-column sum / sumsq (batch-norm stats)
__global__ __launch_bounds__(256) void k_colstats(const float* __restrict__ X, int total,
                                                  int cols, float* __restrict__ sum,
                                                  float* __restrict__ sumsq) {
  __shared__ float ls[256], ls2[256];
  int tid = threadIdx.x;
  int stride = gridDim.x * 256;  // multiple of cols (64/256)
  float s = 0.f, s2 = 0.f;
  for (int i = blockIdx.x * 256 + tid; i < total; i += stride) {
    float v = X[i];
    s += v;
    s2 += v * v;
  }
  ls[tid] = s;
  ls2[tid] = s2;
  __syncthreads();
  if (tid < cols) {
    float a = ls[tid], a2 = ls2[tid];
    for (int j = tid + cols; j < 256; j += cols) { a += ls[j]; a2 += ls2[j]; }
    atomicAdd(&sum[tid], a);
    atomicAdd(&sumsq[tid], a2);
  }
}

// ---------------- bn + leaky on X1f (f32, 64 cols) -> bf16
__global__ __launch_bounds__(256) void k_normb(const float* __restrict__ X,
                                               const float* __restrict__ sum,
                                               const float* __restrict__ sumsq,
                                               const float* __restrict__ g,
                                               const float* __restrict__ b,
                                               ushort* __restrict__ out) {
  __shared__ float sc[64], sh[64];
  int tid = threadIdx.x;
  if (tid < 64) {
    float m = sum[tid] * (1.0f / NPTS);
    float v = sumsq[tid] * (1.0f / NPTS) - m * m;
    float s = g[tid] * rsqrtf(v + EPS);
    sc[tid] = s;
    sh[tid] = b[tid] - m * s;
  }
  __syncthreads();
  const int total4 = NPTS * 16;  // float4s per matrix
  int stride = gridDim.x * 256;
  const float4* X4 = reinterpret_cast<const float4*>(X);
  ushort4* O4 = reinterpret_cast<ushort4*>(out);
  for (int i = blockIdx.x * 256 + tid; i < total4; i += stride) {
    int cb = (i & 15) * 4;
    float4 v = X4[i];
    float a0 = v.x * sc[cb + 0] + sh[cb + 0]; a0 = a0 > 0.f ? a0 : SLOPE * a0;
    float a1 = v.y * sc[cb + 1] + sh[cb + 1]; a1 = a1 > 0.f ? a1 : SLOPE * a1;
    float a2 = v.z * sc[cb + 2] + sh[cb + 2]; a2 = a2 > 0.f ? a2 : SLOPE * a2;
    float a3 = v.w * sc[cb + 3] + sh[cb + 3]; a3 = a3 > 0.f ? a3 : SLOPE * a3;
    ushort4 o; o.x = f2b(a0); o.y = f2b(a1); o.z = f2b(a2); o.w = f2b(a3);
    O4[i] = o;
  }
}

// ---------------- gather + influence -> fk [N, K*D2] bf16. One wave per point.
__global__ __launch_bounds__(256) void k_fk(const ushort* __restrict__ X1b,
                                            const float* __restrict__ xyz,
                                            const int* __restrict__ nidx,
                                            const float* __restrict__ kpp,
                                            ushort* __restrict__ fkb) {
  __shared__ int s_idx[4][32];
  __shared__ float s_w[4][32][16];
  int tid = threadIdx.x;
  int wave = tid >> 6, lane = tid & 63;
  int n = blockIdx.x * 4 + wave;
  if (lane < 32) {
    int nb = nidx[n * NBH + lane];
    s_idx[wave][lane] = nb;
    float rx = xyz[nb * 3 + 0] - xyz[n * 3 + 0];
    float ry = xyz[nb * 3 + 1] - xyz[n * 3 + 1];
    float rz = xyz[nb * 3 + 2] - xyz[n * 3 + 2];
#pragma unroll
    for (int k = 0; k < 15; ++k) {
      float dx = rx - kpp[k * 3 + 0];
      float dy = ry - kpp[k * 3 + 1];
      float dz = rz - kpp[k * 3 + 2];
      float dist = sqrtf(dx * dx + dy * dy + dz * dz);
      s_w[wave][lane][k] = fmaxf(1.0f - dist * (1.0f / INFL), 0.0f);
    }
    s_w[wave][lane][15] = 0.0f;
  }
  __syncthreads();
  float fk[15];
#pragma unroll
  for (int k = 0; k < 15; ++k) fk[k] = 0.f;
  for (int h = 0; h < NBH; ++h) {
    int nb = s_idx[wave][h];
    float v = b2f(X1b[(size_t)nb * 64 + lane]);
    const float4* wp = reinterpret_cast<const float4*>(&s_w[wave][h][0]);
    float4 w0 = wp[0], w1 = wp[1], w2 = wp[2], w3 = wp[3];
    fk[0] += w0.x * v;  fk[1] += w0.y * v;  fk[2] += w0.z * v;  fk[3] += w0.w * v;
    fk[4] += w1.x * v;  fk[5] += w1.y * v;  fk[6] += w1.z * v;  fk[7] += w1.w * v;
    fk[8] += w2.x * v;  fk[9] += w2.y * v;  fk[10] += w2.z * v; fk[11] += w2.w * v;
    fk[12] += w3.x * v; fk[13] += w3.y * v; fk[14] += w3.z * v;
  }
  size_t base = (size_t)n * 960 + lane;
#pragma unroll
  for (int k = 0; k < 15; ++k) fkb[base + k * 64] = f2b(fk[k]);
}

// ---------------- final: out = leaky(bn(Y3)) + bn(YSC)   (YSC == out buffer, in-place)
__global__ __launch_bounds__(256) void k_final(const float* __restrict__ Y3,
                                               const float* __restrict__ YSC,
                                               const float* __restrict__ s3,
                                               const float* __restrict__ ss3,
                                               const float* __restrict__ g2,
                                               const float* __restrict__ b2,
                                               const float* __restrict__ ssc,
                                               const float* __restrict__ sssc,
                                               const float* __restrict__ gsc,
                                               const float* __restrict__ bsc,
                                               float* __restrict__ out) {
  __shared__ float sc3[256], sh3[256], scc[256], shc[256];
  int tid = threadIdx.x;
  {
    float m = s3[tid] * (1.0f / NPTS);
    float v = ss3[tid] * (1.0f / NPTS) - m * m;
    float s = g2[tid] * rsqrtf(v + EPS);
    sc3[tid] = s;
    sh3[tid] = b2[tid] - m * s;
    m = ssc[tid] * (1.0f / NPTS);
    v = sssc[tid] * (1.0f / NPTS) - m * m;
    s = gsc[tid] * rsqrtf(v + EPS);
    scc[tid] = s;
    shc[tid] = bsc[tid] - m * s;
  }
  __syncthreads();
  int total4 = NPTS * COUT / 4;
  int stride = gridDim.x * 256;
  const float4* A4 = reinterpret_cast<const float4*>(Y3);
  const float4* B4 = reinterpret_cast<const float4*>(YSC);
  float4* O4 = reinterpret_cast<float4*>(out);
  for (int i = blockIdx.x * 256 + tid; i < total4; i += stride) {
    int cb = (i & 63) * 4;
    float4 a = A4[i];
    float4 b = B4[i];
    float o0 = a.x * sc3[cb + 0] + sh3[cb + 0]; o0 = o0 > 0.f ? o0 : SLOPE * o0; o0 += b.x * scc[cb + 0] + shc[cb + 0];
    float o1 = a.y * sc3[cb + 1] + sh3[cb + 1]; o1 = o1 > 0.f ? o1 : SLOPE * o1; o1 += b.y * scc[cb + 1] + shc[cb + 1];
    float o2 = a.z * sc3[cb + 2] + sh3[cb + 2]; o2 = o2 > 0.f ? o2 : SLOPE * o2; o2 += b.z * scc[cb + 2] + shc[cb + 2];
    float o3 = a.w * sc3[cb + 3] + sh3[cb + 3]; o3 = o3 > 0.f ? o3 : SLOPE * o3; o3 += b.w * scc[cb + 3] + shc[cb + 3];
    O4[i] = make_float4(o0, o1, o2, o3);
  }
}

extern "C" void kernel_launch(void* const* d_in, const int* in_sizes, int n_in,
                              void* d_out, int out_size, void* d_ws, size_t ws_size,
                              hipStream_t stream) {
  const float* feats = (const float*)d_in[0];
  const float* xyz   = (const float*)d_in[1];
  const int* nidx    = (const int*)d_in[3];
  const float* W1    = (const float*)d_in[4];
  const float* g1    = (const float*)d_in[5];
  const float* b1    = (const float*)d_in[6];
  const float* kpp   = (const float*)d_in[7];
  const float* kw    = (const float*)d_in[8];
  const float* W2    = (const float*)d_in[9];
  const float* g2    = (const float*)d_in[10];
  const float* b2    = (const float*)d_in[11];
  const float* Wsc   = (const float*)d_in[12];
  const float* gsc   = (const float*)d_in[13];
  const float* bsc   = (const float*)d_in[14];
  float* out = (float*)d_out;

  // Workspace (aliased lifetimes, ~184.6 MB):
  //  E [0, 153.6MB): X1f (u1->norm) -> fkb (fk->kpgemm) -> Y3 f32 (u2->final)
  //  A: featsb bf16 20.48MB  (prep -> shortcut gemm)
  //  D: X1b bf16 (norm->fk) -> Y2b bf16 (kpgemm->u2) 10.24MB
  //  B: swizzled weights; F: stats.  YSC lives in d_out.
  char* ws = (char*)d_ws;
  float*  X1f    = (float*)ws;
  ushort* fkb    = (ushort*)ws;
  float*  Y3     = (float*)ws;
  ushort* featsb = (ushort*)(ws + 153600000);
  ushort* X1b    = (ushort*)(ws + 153600000 + 20480000);
  ushort* Y2b    = X1b;
  ushort* w1s    = (ushort*)(ws + 153600000 + 20480000 + 10240000);
  ushort* w2s    = w1s + 8192;
  ushort* wscs   = w2s + 16384;
  ushort* kws    = wscs + 32768;
  float*  ST     = (float*)(kws + 61440);
  float *S1 = ST, *SS1 = ST + 64;
  float *S3 = ST + 128, *SS3 = ST + 384;
  float *SSC = ST + 640, *SSSC = ST + 896;

  hipMemsetAsync(ST, 0, 1152 * sizeof(float), stream);
  k_prep<<<2048, 256, 0, stream>>>(feats, W1, W2, Wsc, kw, featsb, w1s, w2s, wscs, kws);
  // unary_1: X1f = featsb @ W1
  k_gemm_mfma<64, 0><<<1250, 256, 0, stream>>>(featsb, w1s, X1f, nullptr, 128);
  k_colstats<<<512, 256, 0, stream>>>(X1f, NPTS * 64, 64, S1, SS1);
  k_normb<<<1024, 256, 0, stream>>>(X1f, S1, SS1, g1, b1, X1b);
  // KPConv gather + influence -> fk
  k_fk<<<NPTS / 4, 256, 0, stream>>>(X1b, xyz, nidx, kpp, fkb);
  // kp contraction: Y2b = fkb @ kw  (bf16 out)
  k_gemm_mfma<64, 1><<<1250, 256, 0, stream>>>(fkb, kws, nullptr, Y2b, 960);
  // unary_2: Y3 = Y2b @ W2
  k_gemm_mfma<256, 0><<<1250, 256, 0, stream>>>(Y2b, w2s, Y3, nullptr, 64);
  k_colstats<<<512, 256, 0, stream>>>(Y3, NPTS * 256, 256, S3, SS3);
  // shortcut: YSC(=out) = featsb @ Wsc
  k_gemm_mfma<256, 0><<<1250, 256, 0, stream>>>(featsb, wscs, out, nullptr, 128);
  k_colstats<<<512, 256, 0, stream>>>(out, NPTS * 256, 256, SSC, SSSC);
  // out = leaky(bn(Y3)) + bn(out)
  k_final<<<2048, 256, 0, stream>>>(Y3, out, S3, SS3, g2, b2, SSC, SSSC, gsc, bsc, out);
}

// Round 3
// 386.234 us; speedup vs baseline: 2.9822x; 1.3799x over previous
//
#include <hip/hip_runtime.h>
#include <math.h>

#define NPTS 80000
#define NBH 32
#define KP 15
#define CIN 128
#define COUT 256
#define D2 64
#define INFL 0.4f
#define EPS 1e-5f
#define SLOPE 0.2f

typedef __attribute__((ext_vector_type(8))) short short8;
typedef __attribute__((ext_vector_type(4))) float f32x4;

__device__ inline ushort f2b(float x) {
  unsigned u = __float_as_uint(x);
  return (ushort)((u + 0x7FFFu + ((u >> 16) & 1u)) >> 16);  // RNE
}
__device__ inline float b2f(ushort v) { return __uint_as_float(((unsigned)v) << 16); }

// ---------------- prep: feats f32->bf16, weights f32->bf16 swizzled to MFMA B-operand order
// B fragment order: Bsw[chunk][ctile][nn][q][j] <- B[k][n], k=chunk*32+q*8+j, n=ctile*16+nn
__global__ __launch_bounds__(256) void k_prep(const float* __restrict__ feats,
                                              const float* __restrict__ W1,
                                              const float* __restrict__ W2,
                                              const float* __restrict__ Wsc,
                                              const float* __restrict__ kw,
                                              ushort* __restrict__ featsb,
                                              ushort* __restrict__ w1s,
                                              ushort* __restrict__ w2s,
                                              ushort* __restrict__ wscs,
                                              ushort* __restrict__ kws) {
  const int NF4 = NPTS * CIN / 4;
  const int TOT = NF4 + 118784;
  int stride = gridDim.x * 256;
  for (int i = blockIdx.x * 256 + threadIdx.x; i < TOT; i += stride) {
    if (i < NF4) {
      float4 v = reinterpret_cast<const float4*>(feats)[i];
      ushort4 o;
      o.x = f2b(v.x); o.y = f2b(v.y); o.z = f2b(v.z); o.w = f2b(v.w);
      reinterpret_cast<ushort4*>(featsb)[i] = o;
    } else {
      int j = i - NF4;
      const float* src;
      ushort* dst;
      int logN;
      if (j < 8192)       { src = W1;  dst = w1s;  logN = 6; }
      else if (j < 24576) { j -= 8192;  src = W2;  dst = w2s;  logN = 8; }
      else if (j < 57344) { j -= 24576; src = Wsc; dst = wscs; logN = 8; }
      else                { j -= 57344; src = kw;  dst = kws;  logN = 6; }
      int N = 1 << logN, NT = N >> 4;
      int k = j >> logN, n = j & (N - 1);
      int dsti = ((k >> 5) * NT + (n >> 4)) * 512 + (n & 15) * 32 + ((k >> 3) & 3) * 8 + (k & 7);
      dst[dsti] = f2b(src[j]);
    }
  }
}

// ---------------- register-resident MFMA GEMM, bf16 out: C[M x NCOLS] = A[M x K] * B[K x NCOLS]
template <int NCOLS>
__global__ __launch_bounds__(256) void k_gemm_mfma(const ushort* __restrict__ A,
                                                   const ushort* __restrict__ Bsw,
                                                   ushort* __restrict__ Cb, int K) {
  constexpr int NT = NCOLS / 16;
  int tid = threadIdx.x;
  int wave = tid >> 6, lane = tid & 63;
  int nn = lane & 15, q = lane >> 4;
  int row0 = blockIdx.x * 64 + wave * 16;
  f32x4 acc[NT];
#pragma unroll
  for (int c = 0; c < NT; ++c) acc[c] = (f32x4){0.f, 0.f, 0.f, 0.f};
  const ushort* ap = A + (size_t)(row0 + nn) * K + q * 8;
  int nch = K >> 5;
  for (int ch = 0; ch < nch; ++ch) {
    short8 af = *reinterpret_cast<const short8*>(ap + (size_t)ch * 32);
    const ushort* bp = Bsw + (size_t)ch * NT * 512 + nn * 32 + q * 8;
#pragma unroll
    for (int c = 0; c < NT; ++c) {
      short8 bf = *reinterpret_cast<const short8*>(bp + c * 512);
      acc[c] = __builtin_amdgcn_mfma_f32_16x16x32_bf16(af, bf, acc[c], 0, 0, 0);
    }
  }
#pragma unroll
  for (int c = 0; c < NT; ++c)
#pragma unroll
    for (int r = 0; r < 4; ++r)
      Cb[(size_t)(row0 + q * 4 + r) * NCOLS + c * 16 + nn] = f2b(acc[c][r]);
}

// ---------------- per-column sum/sumsq over bf16 matrix (vectorized, LDS reduce)
__global__ __launch_bounds__(256) void k_colstats_b16(const ushort* __restrict__ X, int units,
                                                      int cols, float* __restrict__ sum,
                                                      float* __restrict__ sumsq) {
  __shared__ float ls[2048], ls2[2048];
  int tid = threadIdx.x;
  int stride = gridDim.x * 256;  // divisible by cols/8
  float s[8], s2[8];
#pragma unroll
  for (int k = 0; k < 8; ++k) { s[k] = 0.f; s2[k] = 0.f; }
  for (int i = blockIdx.x * 256 + tid; i < units; i += stride) {
    short8 v = reinterpret_cast<const short8*>(X)[i];
#pragma unroll
    for (int k = 0; k < 8; ++k) {
      float f = b2f((ushort)v[k]);
      s[k] += f;
      s2[k] += f * f;
    }
  }
#pragma unroll
  for (int k = 0; k < 8; ++k) { ls[tid * 8 + k] = s[k]; ls2[tid * 8 + k] = s2[k]; }
  __syncthreads();
  if (tid < cols) {
    int P = cols >> 3;
    float a = 0.f, a2 = 0.f;
    for (int t = (tid >> 3); t < 256; t += P) {
      a += ls[t * 8 + (tid & 7)];
      a2 += ls2[t * 8 + (tid & 7)];
    }
    atomicAdd(&sum[tid], a);
    atomicAdd(&sumsq[tid], a2);
  }
}

// ---------------- bn + leaky on bf16 [N,64] -> bf16
__global__ __launch_bounds__(256) void k_normb(const ushort* __restrict__ X,
                                               const float* __restrict__ sum,
                                               const float* __restrict__ sumsq,
                                               const float* __restrict__ g,
                                               const float* __restrict__ b,
                                               ushort* __restrict__ out) {
  __shared__ float sc[64], sh[64];
  int tid = threadIdx.x;
  if (tid < 64) {
    float m = sum[tid] * (1.0f / NPTS);
    float v = sumsq[tid] * (1.0f / NPTS) - m * m;
    float s = g[tid] * rsqrtf(v + EPS);
    sc[tid] = s;
    sh[tid] = b[tid] - m * s;
  }
  __syncthreads();
  const int units = NPTS * 8;  // short8 units
  int stride = gridDim.x * 256;
  for (int i = blockIdx.x * 256 + tid; i < units; i += stride) {
    short8 v = reinterpret_cast<const short8*>(X)[i];
    int cb = (i & 7) * 8;
    short8 o;
#pragma unroll
    for (int k = 0; k < 8; ++k) {
      float a = b2f((ushort)v[k]) * sc[cb + k] + sh[cb + k];
      a = a > 0.f ? a : SLOPE * a;
      o[k] = (short)f2b(a);
    }
    reinterpret_cast<short8*>(out)[i] = o;
  }
}

// ---------------- fused KPConv: gather -> stage1 MFMA -> stage2 MFMA -> unary2 MFMA
// block = 256 threads (4 waves), 16 points. No fkb materialization.
__global__ __launch_bounds__(256) void k_kpfused(const ushort* __restrict__ X1b,
                                                 const float* __restrict__ xyz,
                                                 const int* __restrict__ nidx,
                                                 const float* __restrict__ kpp,
                                                 const ushort* __restrict__ kws,
                                                 const ushort* __restrict__ w2s,
                                                 ushort* __restrict__ Y3b) {
  __shared__ ushort s_xT[4][64][32];  // [wave][d][h ^ swz] gathered neighbor feats (transposed)
  __shared__ ushort s_fk[30 * 512];   // fk in stage-2 A-operand layout, 16 pts x 960
  __shared__ ushort s_y2[2 * 512];    // Y2 in u2 A-operand layout, 16 pts x 64
  int tid = threadIdx.x;
  int w = tid >> 6, lane = tid & 63;
  int q = lane >> 4, nn = lane & 15;
  int l8 = lane >> 3, c8 = lane & 7;
  int n_base = blockIdx.x * 16;

  int kidx = nn < 15 ? nn : 0;
  float kpx = kpp[kidx * 3 + 0], kpy = kpp[kidx * 3 + 1], kpz = kpp[kidx * 3 + 2];

  for (int p = 0; p < 4; ++p) {
    int n = n_base + w * 4 + p;
    int nb = 0;
    float rx = 0.f, ry = 0.f, rz = 0.f;
    if (lane < 32) {
      nb = nidx[n * NBH + lane];
      rx = xyz[nb * 3 + 0] - xyz[n * 3 + 0];
      ry = xyz[nb * 3 + 1] - xyz[n * 3 + 1];
      rz = xyz[nb * 3 + 2] - xyz[n * 3 + 2];
    }
    // A-frag: af[j] = w[h=q*8+j][kpt=nn] (bf16)
    short8 af;
#pragma unroll
    for (int j = 0; j < 8; ++j) {
      int hh = q * 8 + j;
      float dx = __shfl(rx, hh) - kpx;
      float dy = __shfl(ry, hh) - kpy;
      float dz = __shfl(rz, hh) - kpz;
      float dist = sqrtf(dx * dx + dy * dy + dz * dz);
      float wv = fmaxf(1.0f - dist * (1.0f / INFL), 0.0f);
      if (nn == 15) wv = 0.f;
      af[j] = (short)f2b(wv);
    }
    // gather 32 neighbor rows (coalesced 16B/lane), transpose into s_xT with XOR swizzle
#pragma unroll
    for (int it = 0; it < 4; ++it) {
      int hh = it * 8 + l8;
      int nbh = __shfl(nb, hh);
      short8 v = *reinterpret_cast<const short8*>(X1b + (size_t)nbh * 64 + c8 * 8);
      int hcol = hh ^ ((c8 & 3) << 3);  // key = (d>>3)&3 = c8&3
#pragma unroll
      for (int u = 0; u < 8; ++u) s_xT[w][c8 * 8 + u][hcol] = (ushort)v[u];
    }
    // stage-1 MFMA: fk[kpt][d] = sum_h w[h][kpt] * x[h][d]
    f32x4 acc[4];
#pragma unroll
    for (int c = 0; c < 4; ++c) {
      int d = c * 16 + nn;
      int key = (d >> 3) & 3;
      short8 bf = *reinterpret_cast<const short8*>(&s_xT[w][d][(q ^ key) << 3]);
      acc[c] = __builtin_amdgcn_mfma_f32_16x16x32_bf16(af, bf, (f32x4){0.f, 0.f, 0.f, 0.f}, 0, 0, 0);
    }
    // write fk -> s_fk in stage-2 A layout (kappa = kpt*64 + d), XOR-swizzled (conflict-free)
    int m = w * 4 + p;
#pragma unroll
    for (int c = 0; c < 4; ++c) {
#pragma unroll
      for (int r = 0; r < 4; ++r) {
        int kpt = q * 4 + r;
        if (kpt < 15) {
          int kap = kpt * 64 + c * 16 + nn;
          int ch = kap >> 5, t = kap & 31;
          int tp = t ^ (((ch >> 3) & 3) << 3);
          s_fk[ch * 512 + m * 32 + tp] = f2b(acc[c][r]);
        }
      }
    }
  }
  __syncthreads();

  // stage-2: Y2[16 x 64] = FK[16 x 960] * kw[960 x 64]; wave w owns col tile w
  f32x4 acc2 = (f32x4){0.f, 0.f, 0.f, 0.f};
  for (int ch = 0; ch < 30; ++ch) {
    int key = (ch >> 3) & 3;
    short8 a = *reinterpret_cast<const short8*>(&s_fk[ch * 512 + nn * 32 + ((q ^ key) << 3)]);
    short8 b = *reinterpret_cast<const short8*>(kws + (size_t)ch * 2048 + w * 512 + nn * 32 + q * 8);
    acc2 = __builtin_amdgcn_mfma_f32_16x16x32_bf16(a, b, acc2, 0, 0, 0);
  }
  {
    int e = w * 16 + nn;
    int ch2 = e >> 5, t = e & 31;
#pragma unroll
    for (int r = 0; r < 4; ++r) {
      int mm = q * 4 + r;
      int tp = t ^ (((mm >> 2) & 3) << 3);
      s_y2[ch2 * 512 + mm * 32 + tp] = f2b(acc2[r]);
    }
  }
  __syncthreads();

  // unary_2: Y3[16 x 256] = Y2[16 x 64] * W2[64 x 256]; wave w owns col tiles w*4..w*4+3
  short8 a0, a1;
  {
    int key = (nn >> 2) & 3;
    a0 = *reinterpret_cast<const short8*>(&s_y2[0 * 512 + nn * 32 + ((q ^ key) << 3)]);
    a1 = *reinterpret_cast<const short8*>(&s_y2[1 * 512 + nn * 32 + ((q ^ key) << 3)]);
  }
#pragma unroll
  for (int t4 = 0; t4 < 4; ++t4) {
    int ct = w * 4 + t4;
    short8 b0 = *reinterpret_cast<const short8*>(w2s + (0 * 16 + ct) * 512 + nn * 32 + q * 8);
    short8 b1 = *reinterpret_cast<const short8*>(w2s + (1 * 16 + ct) * 512 + nn * 32 + q * 8);
    f32x4 a = __builtin_amdgcn_mfma_f32_16x16x32_bf16(a0, b0, (f32x4){0.f, 0.f, 0.f, 0.f}, 0, 0, 0);
    a = __builtin_amdgcn_mfma_f32_16x16x32_bf16(a1, b1, a, 0, 0, 0);
#pragma unroll
    for (int r = 0; r < 4; ++r)
      Y3b[(size_t)(n_base + q * 4 + r) * 256 + ct * 16 + nn] = f2b(a[r]);
  }
}

// ---------------- final: out = leaky(bn(Y3b)) + bn(YSCb), f32 out
__global__ __launch_bounds__(256) void k_final(const ushort* __restrict__ Y3,
                                               const ushort* __restrict__ YSC,
                                               const float* __restrict__ s3,
                                               const float* __restrict__ ss3,
                                               const float* __restrict__ g2,
                                               const float* __restrict__ b2,
                                               const float* __restrict__ ssc,
                                               const float* __restrict__ sssc,
                                               const float* __restrict__ gsc,
                                               const float* __restrict__ bsc,
                                               float* __restrict__ out) {
  __shared__ float sc3[256], sh3[256], scc[256], shc[256];
  int tid = threadIdx.x;
  {
    float m = s3[tid] * (1.0f / NPTS);
    float v = ss3[tid] * (1.0f / NPTS) - m * m;
    float s = g2[tid] * rsqrtf(v + EPS);
    sc3[tid] = s;
    sh3[tid] = b2[tid] - m * s;
    m = ssc[tid] * (1.0f / NPTS);
    v = sssc[tid] * (1.0f / NPTS) - m * m;
    s = gsc[tid] * rsqrtf(v + EPS);
    scc[tid] = s;
    shc[tid] = bsc[tid] - m * s;
  }
  __syncthreads();
  const int units = NPTS * 32;  // short8 units per matrix
  int stride = gridDim.x * 256;
  for (int i = blockIdx.x * 256 + tid; i < units; i += stride) {
    short8 a = reinterpret_cast<const short8*>(Y3)[i];
    short8 b = reinterpret_cast<const short8*>(YSC)[i];
    int cb = (i & 31) * 8;
    float o[8];
#pragma unroll
    for (int k = 0; k < 8; ++k) {
      float x = b2f((ushort)a[k]) * sc3[cb + k] + sh3[cb + k];
      x = x > 0.f ? x : SLOPE * x;
      o[k] = x + b2f((ushort)b[k]) * scc[cb + k] + shc[cb + k];
    }
    float4* O4 = reinterpret_cast<float4*>(out + (size_t)i * 8);
    O4[0] = make_float4(o[0], o[1], o[2], o[3]);
    O4[1] = make_float4(o[4], o[5], o[6], o[7]);
  }
}

extern "C" void kernel_launch(void* const* d_in, const int* in_sizes, int n_in,
                              void* d_out, int out_size, void* d_ws, size_t ws_size,
                              hipStream_t stream) {
  const float* feats = (const float*)d_in[0];
  const float* xyz   = (const float*)d_in[1];
  const int* nidx    = (const int*)d_in[3];
  const float* W1    = (const float*)d_in[4];
  const float* g1    = (const float*)d_in[5];
  const float* b1    = (const float*)d_in[6];
  const float* kpp   = (const float*)d_in[7];
  const float* kw    = (const float*)d_in[8];
  const float* W2    = (const float*)d_in[9];
  const float* g2    = (const float*)d_in[10];
  const float* b2    = (const float*)d_in[11];
  const float* Wsc   = (const float*)d_in[12];
  const float* gsc   = (const float*)d_in[13];
  const float* bsc   = (const float*)d_in[14];
  float* out = (float*)d_out;

  // workspace (bytes): featsb 20.48M | X1r 10.24M | X1b 10.24M | Y3b 40.96M | YSCb 40.96M | weights | stats
  char* ws = (char*)d_ws;
  ushort* featsb = (ushort*)ws;
  ushort* X1r    = (ushort*)(ws + 20480000);
  ushort* X1b    = (ushort*)(ws + 30720000);
  ushort* Y3b    = (ushort*)(ws + 40960000);
  ushort* YSCb   = (ushort*)(ws + 81920000);
  ushort* w1s    = (ushort*)(ws + 122880000);
  ushort* w2s    = w1s + 8192;
  ushort* wscs   = w2s + 16384;
  ushort* kws    = wscs + 32768;
  float*  ST     = (float*)(kws + 61440);
  float *S1 = ST, *SS1 = ST + 64;
  float *S3 = ST + 128, *SS3 = ST + 384;
  float *SSC = ST + 640, *SSSC = ST + 896;

  hipMemsetAsync(ST, 0, 1152 * sizeof(float), stream);
  k_prep<<<2048, 256, 0, stream>>>(feats, W1, W2, Wsc, kw, featsb, w1s, w2s, wscs, kws);
  // unary_1
  k_gemm_mfma<64><<<1250, 256, 0, stream>>>(featsb, w1s, X1r, 128);
  k_colstats_b16<<<256, 256, 0, stream>>>(X1r, NPTS * 8, 64, S1, SS1);
  k_normb<<<512, 256, 0, stream>>>(X1r, S1, SS1, g1, b1, X1b);
  // shortcut (independent)
  k_gemm_mfma<256><<<1250, 256, 0, stream>>>(featsb, wscs, YSCb, 128);
  k_colstats_b16<<<256, 256, 0, stream>>>(YSCb, NPTS * 32, 256, SSC, SSSC);
  // fused KPConv + unary_2
  k_kpfused<<<NPTS / 16, 256, 0, stream>>>(X1b, xyz, nidx, kpp, kws, w2s, Y3b);
  k_colstats_b16<<<256, 256, 0, stream>>>(Y3b, NPTS * 32, 256, S3, SS3);
  // out = leaky(bn(Y3b)) + bn(YSCb)
  k_final<<<1024, 256, 0, stream>>>(Y3b, YSCb, S3, SS3, g2, b2, SSC, SSSC, gsc, bsc, out);
}